// Round 1
// baseline (2030.562 us; speedup 1.0000x reference)
//
#include <hip/hip_runtime.h>
#include <math.h>

#define B_   8
#define CIN  64
#define N_   3136
#define DIN  576
#define CO   128
#define EPS  1e-5f
#define QSCALE 0.0883883476483184f   // 1/sqrt(128)

__device__ __forceinline__ float gelu_exact(float x) {
    return 0.5f * x * (1.0f + erff(x * 0.7071067811865475f));
}

// ---------------- K1: im2col + QKV GEMM + bias + LayerNorm ----------------
__global__ __launch_bounds__(256) void qkv_kernel(
    const float* __restrict__ x,
    const float* __restrict__ Wq, const float* __restrict__ bq,
    const float* __restrict__ gq, const float* __restrict__ btq,
    const float* __restrict__ Wk, const float* __restrict__ bk,
    const float* __restrict__ gk, const float* __restrict__ btk,
    const float* __restrict__ Wv, const float* __restrict__ bv,
    const float* __restrict__ gv, const float* __restrict__ btv,
    float* __restrict__ qo, float* __restrict__ ko, float* __restrict__ vo)
{
    __shared__ float At[64][36];    // A chunk transposed: [k][row], padded
    __shared__ float Wc[64][132];   // W chunk: [k][col], padded
    const int b   = blockIdx.y;
    const int n0  = blockIdx.x * 32;
    const int tid = threadIdx.x;
    const int cg  = tid & 31;   // col group: cols cg*4..+3
    const int rg  = tid >> 5;   // row group: rows rg*4..+3

    float acc[3][4][4];
    #pragma unroll
    for (int t = 0; t < 3; ++t)
        #pragma unroll
        for (int i = 0; i < 4; ++i)
            #pragma unroll
            for (int j = 0; j < 4; ++j) acc[t][i][j] = 0.f;

    const float* Ws[3] = {Wq, Wk, Wv};

    for (int kc = 0; kc < DIN; kc += 64) {
        #pragma unroll
        for (int t = 0; t < 3; ++t) {
            __syncthreads();
            if (t == 0) {
                // im2col stage: 64 feats x 32 rows
                for (int e = tid; e < 2048; e += 256) {
                    int f = e >> 5, r = e & 31;
                    int d = kc + f;
                    int c  = d / 9, r9 = d - c * 9;
                    int kh = r9 / 3, kw = r9 - kh * 3;
                    int n  = n0 + r;
                    int oh = n / 56, ow = n - oh * 56;
                    int ih = oh + kh - 1, iw = ow + kw - 1;
                    float val = 0.f;
                    if ((unsigned)ih < 56u && (unsigned)iw < 56u)
                        val = x[((b * CIN + c) * 56 + ih) * 56 + iw];
                    At[f][r] = val;
                }
            }
            const float* W = Ws[t];
            for (int e = tid; e < 2048; e += 256) {
                int kk = e >> 5, j4 = e & 31;
                *reinterpret_cast<float4*>(&Wc[kk][j4 * 4]) =
                    *reinterpret_cast<const float4*>(&W[(kc + kk) * CO + j4 * 4]);
            }
            __syncthreads();
            #pragma unroll 4
            for (int kk = 0; kk < 64; ++kk) {
                float4 a = *reinterpret_cast<const float4*>(&At[kk][rg * 4]);
                float4 w = *reinterpret_cast<const float4*>(&Wc[kk][cg * 4]);
                float av[4] = {a.x, a.y, a.z, a.w};
                float wv[4] = {w.x, w.y, w.z, w.w};
                #pragma unroll
                for (int i = 0; i < 4; ++i)
                    #pragma unroll
                    for (int j = 0; j < 4; ++j)
                        acc[t][i][j] = fmaf(av[i], wv[j], acc[t][i][j]);
            }
        }
    }

    // bias + LayerNorm + write, per type
    const float* bias[3] = {bq, bk, bv};
    const float* gg[3]   = {gq, gk, gv};
    const float* bb[3]   = {btq, btk, btv};
    float* outp[3]       = {qo, ko, vo};
    float* outT = &Wc[0][0];     // reuse LDS, row stride 132
    const int row = tid >> 3;
    const int sub = tid & 7;

    #pragma unroll
    for (int t = 0; t < 3; ++t) {
        __syncthreads();
        #pragma unroll
        for (int i = 0; i < 4; ++i) {
            int r = rg * 4 + i, c = cg * 4;
            float4 o;
            o.x = acc[t][i][0] + bias[t][c + 0];
            o.y = acc[t][i][1] + bias[t][c + 1];
            o.z = acc[t][i][2] + bias[t][c + 2];
            o.w = acc[t][i][3] + bias[t][c + 3];
            *reinterpret_cast<float4*>(&outT[r * 132 + c]) = o;
        }
        __syncthreads();
        float s = 0.f, ss = 0.f;
        #pragma unroll
        for (int u = 0; u < 16; ++u) {
            float vv = outT[row * 132 + sub * 16 + u];
            s += vv; ss += vv * vv;
        }
        #pragma unroll
        for (int off = 1; off < 8; off <<= 1) {
            s  += __shfl_xor(s, off);
            ss += __shfl_xor(ss, off);
        }
        float mean = s * (1.f / 128.f);
        float var  = ss * (1.f / 128.f) - mean * mean;
        float rstd = rsqrtf(var + EPS);
        float* op = outp[t] + (size_t)(b * N_ + n0 + row) * CO;
        #pragma unroll
        for (int u4 = 0; u4 < 4; ++u4) {
            int c = sub * 16 + u4 * 4;
            float4 o;
            o.x = (outT[row * 132 + c + 0] - mean) * rstd * gg[t][c + 0] + bb[t][c + 0];
            o.y = (outT[row * 132 + c + 1] - mean) * rstd * gg[t][c + 1] + bb[t][c + 1];
            o.z = (outT[row * 132 + c + 2] - mean) * rstd * gg[t][c + 2] + bb[t][c + 2];
            o.w = (outT[row * 132 + c + 3] - mean) * rstd * gg[t][c + 3] + bb[t][c + 3];
            *reinterpret_cast<float4*>(&op[c]) = o;
        }
    }
}

// ---------------- K2: flash attention ----------------
__global__ __launch_bounds__(256) void attn_kernel(
    const float* __restrict__ q, const float* __restrict__ k,
    const float* __restrict__ v, float* __restrict__ ctx)
{
    __shared__ float Qs[32][132];
    __shared__ float Kt[128][36];   // [d][c]
    __shared__ float Vs[32][132];
    __shared__ float Ss[32][36];
    const int b   = blockIdx.y;
    const int n0  = blockIdx.x * 32;
    const int tid = threadIdx.x;
    const int row = tid >> 3;
    const int sub = tid & 7;
    const int cJ  = sub * 4;    // score cols
    const int c0  = sub * 16;   // output cols

    for (int e = tid; e < 1024; e += 256) {
        int r = e >> 5, d4 = e & 31;
        float4 qv = *reinterpret_cast<const float4*>(&q[(size_t)(b * N_ + n0 + r) * CO + d4 * 4]);
        qv.x *= QSCALE; qv.y *= QSCALE; qv.z *= QSCALE; qv.w *= QSCALE;
        *reinterpret_cast<float4*>(&Qs[r][d4 * 4]) = qv;
    }
    float m = -1e30f, l = 0.f;
    float acc[16];
    #pragma unroll
    for (int i = 0; i < 16; ++i) acc[i] = 0.f;
    __syncthreads();

    for (int kt = 0; kt < 98; ++kt) {
        const int kb = kt * 32;
        for (int e = tid; e < 4096; e += 256) {
            int c = e >> 7, d = e & 127;
            Kt[d][c] = k[(size_t)(b * N_ + kb + c) * CO + d];
        }
        for (int e = tid; e < 1024; e += 256) {
            int c = e >> 5, d4 = e & 31;
            *reinterpret_cast<float4*>(&Vs[c][d4 * 4]) =
                *reinterpret_cast<const float4*>(&v[(size_t)(b * N_ + kb + c) * CO + d4 * 4]);
        }
        __syncthreads();

        float s0 = 0, s1 = 0, s2 = 0, s3 = 0;
        #pragma unroll 4
        for (int d = 0; d < 128; ++d) {
            float qd = Qs[row][d];
            float4 kk4 = *reinterpret_cast<const float4*>(&Kt[d][cJ]);
            s0 = fmaf(qd, kk4.x, s0);
            s1 = fmaf(qd, kk4.y, s1);
            s2 = fmaf(qd, kk4.z, s2);
            s3 = fmaf(qd, kk4.w, s3);
        }
        float mx = fmaxf(fmaxf(s0, s1), fmaxf(s2, s3));
        #pragma unroll
        for (int off = 1; off < 8; off <<= 1) mx = fmaxf(mx, __shfl_xor(mx, off));
        float mNew = fmaxf(m, mx);
        float p0 = __expf(s0 - mNew), p1 = __expf(s1 - mNew);
        float p2 = __expf(s2 - mNew), p3 = __expf(s3 - mNew);
        float sc = __expf(m - mNew);
        float rs = p0 + p1 + p2 + p3;
        #pragma unroll
        for (int off = 1; off < 8; off <<= 1) rs += __shfl_xor(rs, off);
        l = l * sc + rs;
        m = mNew;
        float4 pv = {p0, p1, p2, p3};
        *reinterpret_cast<float4*>(&Ss[row][cJ]) = pv;
        __syncthreads();

        #pragma unroll
        for (int i = 0; i < 16; ++i) acc[i] *= sc;
        for (int c = 0; c < 32; ++c) {
            float p = Ss[row][c];
            const float* vrow = &Vs[c][c0];
            #pragma unroll
            for (int u = 0; u < 4; ++u) {
                float4 vv = *reinterpret_cast<const float4*>(&vrow[u * 4]);
                acc[u * 4 + 0] = fmaf(p, vv.x, acc[u * 4 + 0]);
                acc[u * 4 + 1] = fmaf(p, vv.y, acc[u * 4 + 1]);
                acc[u * 4 + 2] = fmaf(p, vv.z, acc[u * 4 + 2]);
                acc[u * 4 + 3] = fmaf(p, vv.w, acc[u * 4 + 3]);
            }
        }
        __syncthreads();
    }
    float inv_l = 1.f / l;
    float* op = &ctx[(size_t)(b * N_ + n0 + row) * CO + c0];
    #pragma unroll
    for (int u = 0; u < 4; ++u) {
        float4 o = {acc[u * 4] * inv_l, acc[u * 4 + 1] * inv_l,
                    acc[u * 4 + 2] * inv_l, acc[u * 4 + 3] * inv_l};
        *reinterpret_cast<float4*>(&op[u * 4]) = o;
    }
}

// ---------------- K3: LayerNorm + GELU (in place) ----------------
__global__ __launch_bounds__(256) void ln_gelu_kernel(
    float* __restrict__ ctx, const float* __restrict__ g, const float* __restrict__ be)
{
    const int wave = threadIdx.x >> 6;
    const int lane = threadIdx.x & 63;
    const size_t r = (size_t)blockIdx.x * 4 + wave;
    float* p = ctx + r * CO + lane * 2;
    float2 xv = *reinterpret_cast<float2*>(p);
    float s = xv.x + xv.y;
    float ss = xv.x * xv.x + xv.y * xv.y;
    #pragma unroll
    for (int off = 1; off < 64; off <<= 1) {
        s  += __shfl_xor(s, off);
        ss += __shfl_xor(ss, off);
    }
    float mean = s * (1.f / 128.f);
    float var  = ss * (1.f / 128.f) - mean * mean;
    float rstd = rsqrtf(var + EPS);
    int c = lane * 2;
    float y0 = gelu_exact((xv.x - mean) * rstd * g[c] + be[c]);
    float y1 = gelu_exact((xv.y - mean) * rstd * g[c + 1] + be[c + 1]);
    *reinterpret_cast<float2*>(p) = make_float2(y0, y1);
}

// ---------------- K4a: per-chunk partial sums for gate + BN stats ----------------
__global__ __launch_bounds__(128) void gate_part_kernel(
    const float* __restrict__ ctx, const float* __restrict__ Wca,
    float* __restrict__ Gp, float* __restrict__ S1p, float* __restrict__ S2p)
{
    const int ch = blockIdx.x;   // 0..31
    const int b  = blockIdx.y;
    const int c  = threadIdx.x;
    float g = 0, s1 = 0, s2 = 0;
    for (int i = 0; i < 98; ++i) {
        int n = ch * 98 + i;
        float vv = ctx[(size_t)(b * N_ + n) * CO + c];
        float w = Wca[n];
        g  = fmaf(vv, w, g);
        s1 += vv;
        s2 = fmaf(vv, vv, s2);
    }
    int idx = (ch * B_ + b) * CO + c;
    Gp[idx] = g; S1p[idx] = s1; S2p[idx] = s2;
}

// ---------------- K4c: finalize gate + BN stats ----------------
__global__ __launch_bounds__(128) void bn_stats_kernel(
    const float* __restrict__ Gp, const float* __restrict__ S1p, const float* __restrict__ S2p,
    const float* __restrict__ bca, float* __restrict__ Gate,
    float* __restrict__ mu, float* __restrict__ rstd)
{
    const int c = threadIdx.x;
    float msum = 0, sqsum = 0;
    for (int b = 0; b < B_; ++b) {
        float g = 0, s1 = 0, s2 = 0;
        for (int ch = 0; ch < 32; ++ch) {
            int idx = (ch * B_ + b) * CO + c;
            g += Gp[idx]; s1 += S1p[idx]; s2 += S2p[idx];
        }
        g += bca[0];
        Gate[b * CO + c] = g;
        msum  = fmaf(g, s1, msum);
        sqsum = fmaf(g * g, s2, sqsum);
    }
    float mean = msum * (1.f / 25088.f);
    float var  = sqsum * (1.f / 25088.f) - mean * mean;
    mu[c] = mean;
    rstd[c] = rsqrtf(var + EPS);
}

// ---------------- K5: transpose + gate + BN + GELU ----------------
__global__ __launch_bounds__(256) void out_kernel(
    const float* __restrict__ ctx, const float* __restrict__ Gate,
    const float* __restrict__ mu, const float* __restrict__ rstd,
    const float* __restrict__ bng, const float* __restrict__ bnb,
    float* __restrict__ out)
{
    __shared__ float T[32][33];
    const int nt = blockIdx.x, ct = blockIdx.y, b = blockIdx.z;
    const int n0 = nt * 32, c0 = ct * 32;
    const int tid = threadIdx.x;
    const int j = tid & 31, i0 = tid >> 5;
    #pragma unroll
    for (int p = 0; p < 4; ++p) {
        int i = i0 + p * 8;
        T[i][j] = ctx[(size_t)(b * N_ + n0 + i) * CO + c0 + j];
    }
    __syncthreads();
    #pragma unroll
    for (int p = 0; p < 4; ++p) {
        int cl = i0 + p * 8;
        int c = c0 + cl;
        float val = Gate[b * CO + c] * T[j][cl];
        val = (val - mu[c]) * rstd[c] * bng[c] + bnb[c];
        out[((size_t)(b * CO + c)) * N_ + n0 + j] = gelu_exact(val);
    }
}

extern "C" void kernel_launch(void* const* d_in, const int* in_sizes, int n_in,
                              void* d_out, int out_size, void* d_ws, size_t ws_size,
                              hipStream_t stream)
{
    const float* x   = (const float*)d_in[0];
    const float* Wq  = (const float*)d_in[1];
    const float* bq  = (const float*)d_in[2];
    const float* gq  = (const float*)d_in[3];
    const float* btq = (const float*)d_in[4];
    const float* Wk  = (const float*)d_in[5];
    const float* bk  = (const float*)d_in[6];
    const float* gk  = (const float*)d_in[7];
    const float* btk = (const float*)d_in[8];
    const float* Wv  = (const float*)d_in[9];
    const float* bv  = (const float*)d_in[10];
    const float* gv  = (const float*)d_in[11];
    const float* btv = (const float*)d_in[12];
    const float* g1  = (const float*)d_in[13];
    const float* b1  = (const float*)d_in[14];
    const float* Wca = (const float*)d_in[15];
    const float* bca = (const float*)d_in[16];
    const float* bng = (const float*)d_in[17];
    const float* bnb = (const float*)d_in[18];
    float* out = (float*)d_out;

    float* ws = (float*)d_ws;
    const size_t SZ = (size_t)B_ * N_ * CO;   // 3,211,264 floats
    float* qb   = ws;
    float* kb   = ws + SZ;
    float* vb   = ws + 2 * SZ;
    float* cb   = ws + 3 * SZ;
    float* Gp   = ws + 4 * SZ;
    float* S1p  = Gp + 32768;
    float* S2p  = S1p + 32768;
    float* Gate = S2p + 32768;
    float* muv  = Gate + 1024;
    float* rsv  = muv + 128;

    qkv_kernel<<<dim3(98, 8), 256, 0, stream>>>(x, Wq, bq, gq, btq,
                                                Wk, bk, gk, btk,
                                                Wv, bv, gv, btv, qb, kb, vb);
    attn_kernel<<<dim3(98, 8), 256, 0, stream>>>(qb, kb, vb, cb);
    ln_gelu_kernel<<<dim3(6272), 256, 0, stream>>>(cb, g1, b1);
    gate_part_kernel<<<dim3(32, 8), 128, 0, stream>>>(cb, Wca, Gp, S1p, S2p);
    bn_stats_kernel<<<dim3(1), 128, 0, stream>>>(Gp, S1p, S2p, bca, Gate, muv, rsv);
    out_kernel<<<dim3(98, 4, 8), 256, 0, stream>>>(cb, Gate, muv, rsv, bng, bnb, out);
}

// Round 2
// 486.655 us; speedup vs baseline: 4.1725x; 4.1725x over previous
//
#include <hip/hip_runtime.h>
#include <math.h>

#define B_   8
#define CIN  64
#define N_   3136
#define DIN  576
#define CO   128
#define EPS  1e-5f
#define QSCALE 0.0883883476483184f   // 1/sqrt(128)

typedef __attribute__((ext_vector_type(8))) short sh8;     // 8 bf16 (4 VGPRs)
typedef __attribute__((ext_vector_type(16))) float fx16;   // MFMA 32x32 accum

__device__ __forceinline__ float gelu_exact(float x) {
    return 0.5f * x * (1.0f + erff(x * 0.7071067811865475f));
}
__device__ __forceinline__ unsigned short f2bf(float f) {   // RN-even f32->bf16
    unsigned u = __float_as_uint(f);
    u += 0x7fffu + ((u >> 16) & 1u);
    return (unsigned short)(u >> 16);
}
__device__ __forceinline__ unsigned pack2(float a, float b) {
    return (unsigned)f2bf(a) | ((unsigned)f2bf(b) << 16);
}

// ---------------- K1: im2col + QKV GEMM (fp32) + bias + LayerNorm -> bf16 ----------------
// Outputs: q (pre-scaled by 1/sqrt(128)) [B][N][128] bf16, k [B][N][128] bf16,
//          v TRANSPOSED [B][128][N] bf16.
__global__ __launch_bounds__(256) void qkv_kernel(
    const float* __restrict__ x,
    const float* __restrict__ Wq, const float* __restrict__ bq,
    const float* __restrict__ gq, const float* __restrict__ btq,
    const float* __restrict__ Wk, const float* __restrict__ bk,
    const float* __restrict__ gk, const float* __restrict__ btk,
    const float* __restrict__ Wv, const float* __restrict__ bv,
    const float* __restrict__ gv, const float* __restrict__ btv,
    unsigned short* __restrict__ qo, unsigned short* __restrict__ ko,
    unsigned short* __restrict__ vt)
{
    __shared__ float At[64][36];
    __shared__ float Wc[64][132];
    const int b   = blockIdx.y;
    const int n0  = blockIdx.x * 32;
    const int tid = threadIdx.x;
    const int cg  = tid & 31;
    const int rg  = tid >> 5;

    float acc[3][4][4];
    #pragma unroll
    for (int t = 0; t < 3; ++t)
        #pragma unroll
        for (int i = 0; i < 4; ++i)
            #pragma unroll
            for (int j = 0; j < 4; ++j) acc[t][i][j] = 0.f;

    const float* Ws[3] = {Wq, Wk, Wv};

    for (int kc = 0; kc < DIN; kc += 64) {
        #pragma unroll
        for (int t = 0; t < 3; ++t) {
            __syncthreads();
            if (t == 0) {
                for (int e = tid; e < 2048; e += 256) {
                    int f = e >> 5, r = e & 31;
                    int d = kc + f;
                    int c  = d / 9, r9 = d - c * 9;
                    int kh = r9 / 3, kw = r9 - kh * 3;
                    int n  = n0 + r;
                    int oh = n / 56, ow = n - oh * 56;
                    int ih = oh + kh - 1, iw = ow + kw - 1;
                    float val = 0.f;
                    if ((unsigned)ih < 56u && (unsigned)iw < 56u)
                        val = x[((b * CIN + c) * 56 + ih) * 56 + iw];
                    At[f][r] = val;
                }
            }
            const float* W = Ws[t];
            for (int e = tid; e < 2048; e += 256) {
                int kk = e >> 5, j4 = e & 31;
                *reinterpret_cast<float4*>(&Wc[kk][j4 * 4]) =
                    *reinterpret_cast<const float4*>(&W[(kc + kk) * CO + j4 * 4]);
            }
            __syncthreads();
            #pragma unroll 4
            for (int kk = 0; kk < 64; ++kk) {
                float4 a = *reinterpret_cast<const float4*>(&At[kk][rg * 4]);
                float4 w = *reinterpret_cast<const float4*>(&Wc[kk][cg * 4]);
                float av[4] = {a.x, a.y, a.z, a.w};
                float wv[4] = {w.x, w.y, w.z, w.w};
                #pragma unroll
                for (int i = 0; i < 4; ++i)
                    #pragma unroll
                    for (int j = 0; j < 4; ++j)
                        acc[t][i][j] = fmaf(av[i], wv[j], acc[t][i][j]);
            }
        }
    }

    const float* bias[3] = {bq, bk, bv};
    const float* gg[3]   = {gq, gk, gv};
    const float* bb[3]   = {btq, btk, btv};
    float* outT = &Wc[0][0];     // reuse LDS, row stride 132
    const int row = tid >> 3;
    const int sub = tid & 7;

    #pragma unroll
    for (int t = 0; t < 3; ++t) {
        __syncthreads();
        #pragma unroll
        for (int i = 0; i < 4; ++i) {
            int r = rg * 4 + i, c = cg * 4;
            float4 o;
            o.x = acc[t][i][0] + bias[t][c + 0];
            o.y = acc[t][i][1] + bias[t][c + 1];
            o.z = acc[t][i][2] + bias[t][c + 2];
            o.w = acc[t][i][3] + bias[t][c + 3];
            *reinterpret_cast<float4*>(&outT[r * 132 + c]) = o;
        }
        __syncthreads();
        float s = 0.f, ss = 0.f;
        #pragma unroll
        for (int u = 0; u < 16; ++u) {
            float vv = outT[row * 132 + sub * 16 + u];
            s += vv; ss += vv * vv;
        }
        #pragma unroll
        for (int off = 1; off < 8; off <<= 1) {
            s  += __shfl_xor(s, off);
            ss += __shfl_xor(ss, off);
        }
        float mean = s * (1.f / 128.f);
        float var  = ss * (1.f / 128.f) - mean * mean;
        float rstd = rsqrtf(var + EPS);

        if (t < 2) {
            float extra = (t == 0) ? QSCALE : 1.f;
            unsigned short* op = (t == 0 ? qo : ko) + (size_t)(b * N_ + n0 + row) * CO;
            #pragma unroll
            for (int u4 = 0; u4 < 4; ++u4) {
                int c = sub * 16 + u4 * 4;
                ushort4 o4;
                o4.x = f2bf(((outT[row * 132 + c + 0] - mean) * rstd * gg[t][c + 0] + bb[t][c + 0]) * extra);
                o4.y = f2bf(((outT[row * 132 + c + 1] - mean) * rstd * gg[t][c + 1] + bb[t][c + 1]) * extra);
                o4.z = f2bf(((outT[row * 132 + c + 2] - mean) * rstd * gg[t][c + 2] + bb[t][c + 2]) * extra);
                o4.w = f2bf(((outT[row * 132 + c + 3] - mean) * rstd * gg[t][c + 3] + bb[t][c + 3]) * extra);
                *reinterpret_cast<ushort4*>(&op[c]) = o4;
            }
        } else {
            // V: normalize in place, then transposed bf16 write V^T[b][c][n]
            #pragma unroll
            for (int u = 0; u < 16; ++u) {
                int c = sub * 16 + u;
                outT[row * 132 + c] = (outT[row * 132 + c] - mean) * rstd * gg[2][c] + bb[2][c];
            }
            __syncthreads();
            int c = tid & 127, half = tid >> 7;
            uint4 w0, w1;
            w0.x = pack2(outT[(half * 16 +  0) * 132 + c], outT[(half * 16 +  1) * 132 + c]);
            w0.y = pack2(outT[(half * 16 +  2) * 132 + c], outT[(half * 16 +  3) * 132 + c]);
            w0.z = pack2(outT[(half * 16 +  4) * 132 + c], outT[(half * 16 +  5) * 132 + c]);
            w0.w = pack2(outT[(half * 16 +  6) * 132 + c], outT[(half * 16 +  7) * 132 + c]);
            w1.x = pack2(outT[(half * 16 +  8) * 132 + c], outT[(half * 16 +  9) * 132 + c]);
            w1.y = pack2(outT[(half * 16 + 10) * 132 + c], outT[(half * 16 + 11) * 132 + c]);
            w1.z = pack2(outT[(half * 16 + 12) * 132 + c], outT[(half * 16 + 13) * 132 + c]);
            w1.w = pack2(outT[(half * 16 + 14) * 132 + c], outT[(half * 16 + 15) * 132 + c]);
            unsigned short* vp = vt + (size_t)(b * CO + c) * N_ + n0 + half * 16;
            *reinterpret_cast<uint4*>(vp)     = w0;
            *reinterpret_cast<uint4*>(vp + 8) = w1;
        }
    }
}

// ---------------- K2: MFMA flash attention + fused LN1 + GELU ----------------
// 2 waves/block, 32 q-rows/wave, KVBLK=64, mfma_f32_32x32x16_bf16.
// Swapped QK^T (S^T = K @ Q^T) and swapped PV (ctx^T = V^T @ P^T) keep
// softmax/rescale state at q = lane&31 for every lane.
__global__ __launch_bounds__(128, 2) void attn_kernel(
    const unsigned short* __restrict__ Qb, const unsigned short* __restrict__ Kb,
    const unsigned short* __restrict__ Vt, const float* __restrict__ g1,
    const float* __restrict__ b1, float* __restrict__ ctx)
{
    __shared__ alignas(16) char KsB[16384];      // K tile [64][128] bf16, swizzled
    __shared__ alignas(16) char VsB[16384];      // V^T tile [128][64] bf16, swizzled
    __shared__ alignas(16) char PsB[2][4096];    // per-wave P [32 q][64 kv] bf16, swizzled
    __shared__ float g1s[128], b1s[128];

    const int b   = blockIdx.y;
    const int n0  = blockIdx.x * 64;
    const int tid = threadIdx.x;
    const int w   = tid >> 6;
    const int l   = tid & 63;
    const int h   = l >> 5;
    const int lq  = l & 31;
    const int qx  = (lq & 7) << 4;               // P/V swizzle key

    if (tid < 128) { g1s[tid] = g1[tid]; b1s[tid] = b1[tid]; }

    // Q fragments in registers: qr[kc] = Q[q=lq][16*kc + 8*h .. +7]
    sh8 qr[8];
    {
        const unsigned short* qp = Qb + (size_t)(b * N_ + n0 + w * 32 + lq) * CO + 8 * h;
        #pragma unroll
        for (int kc = 0; kc < 8; ++kc)
            qr[kc] = *reinterpret_cast<const sh8*>(qp + 16 * kc);
    }

    fx16 acc[4];
    #pragma unroll
    for (int mt = 0; mt < 4; ++mt)
        #pragma unroll
        for (int e = 0; e < 16; ++e) acc[mt][e] = 0.f;
    float m = -1e30f, ll = 0.f;

    const char* kgb = (const char*)(Kb + (size_t)b * N_ * CO);
    const char* vgb = (const char*)(Vt + (size_t)b * CO * N_);

    for (int kt = 0; kt < 49; ++kt) {
        const int kb = kt * 64;
        __syncthreads();   // previous tile fully consumed
        // ---- stage K tile: linear LDS dest, inverse-swizzled global source ----
        #pragma unroll
        for (int j = 0; j < 8; ++j) {
            int o   = (w * 8 + j) * 1024 + l * 16;
            int row = o >> 8;
            int cc  = (o & 255) ^ ((row & 15) << 4);
            const char* src = kgb + (size_t)(kb + row) * 256 + cc;
            __builtin_amdgcn_global_load_lds(
                (const __attribute__((address_space(1))) void*)src,
                (__attribute__((address_space(3))) void*)(KsB + (w * 8 + j) * 1024),
                16, 0, 0);
        }
        // ---- stage V^T tile ----
        #pragma unroll
        for (int j = 0; j < 8; ++j) {
            int o  = (w * 8 + j) * 1024 + l * 16;
            int d  = o >> 7;
            int cc = (o & 127) ^ ((d & 7) << 4);
            const char* src = vgb + ((size_t)d * N_ + kb) * 2 + cc;
            __builtin_amdgcn_global_load_lds(
                (const __attribute__((address_space(1))) void*)src,
                (__attribute__((address_space(3))) void*)(VsB + (w * 8 + j) * 1024),
                16, 0, 0);
        }
        asm volatile("s_waitcnt vmcnt(0)" ::: "memory");
        __syncthreads();

        // ---- QK^T (swapped): S^T[kv][q] ----
        fx16 s[2];
        #pragma unroll
        for (int f = 0; f < 2; ++f)
            #pragma unroll
            for (int e = 0; e < 16; ++e) s[f][e] = 0.f;
        #pragma unroll
        for (int kc = 0; kc < 8; ++kc) {
            int cb = 32 * kc + 16 * h;
            sh8 a0 = *reinterpret_cast<const sh8*>(KsB + (lq       * 256 + (cb ^ ((lq & 15) << 4))));
            sh8 a1 = *reinterpret_cast<const sh8*>(KsB + ((lq + 32) * 256 + (cb ^ (((lq + 32) & 15) << 4))));
            s[0] = __builtin_amdgcn_mfma_f32_32x32x16_bf16(a0, qr[kc], s[0], 0, 0, 0);
            s[1] = __builtin_amdgcn_mfma_f32_32x32x16_bf16(a1, qr[kc], s[1], 0, 0, 0);
        }

        // ---- online softmax (q = lq lane-local; pair lane l^32 has other kv half) ----
        float pm = -1e30f;
        #pragma unroll
        for (int f = 0; f < 2; ++f)
            #pragma unroll
            for (int e = 0; e < 16; ++e) pm = fmaxf(pm, s[f][e]);
        pm = fmaxf(pm, __shfl_xor(pm, 32));
        float mn = fmaxf(m, pm);
        float sc = __expf(m - mn);
        float p[2][16];
        float rs = 0.f;
        #pragma unroll
        for (int f = 0; f < 2; ++f)
            #pragma unroll
            for (int e = 0; e < 16; ++e) {
                float pe = __expf(s[f][e] - mn);
                p[f][e] = pe; rs += pe;
            }
        rs += __shfl_xor(rs, 32);
        ll = ll * sc + rs;
        m = mn;
        #pragma unroll
        for (int mt = 0; mt < 4; ++mt)
            #pragma unroll
            for (int e = 0; e < 16; ++e) acc[mt][e] *= sc;

        // ---- P -> bf16 -> wave-private swizzled LDS [q][kv] ----
        {
            char* pw = PsB[w] + lq * 128;
            #pragma unroll
            for (int f = 0; f < 2; ++f)
                #pragma unroll
                for (int j = 0; j < 4; ++j) {
                    uint2 wv;
                    wv.x = pack2(p[f][4 * j + 0], p[f][4 * j + 1]);
                    wv.y = pack2(p[f][4 * j + 2], p[f][4 * j + 3]);
                    *reinterpret_cast<uint2*>(pw + ((64 * f + 16 * j + 8 * h) ^ qx)) = wv;
                }
        }

        // ---- PV (swapped): ctx^T[d][q] += V^T @ P^T ----
        #pragma unroll
        for (int kc = 0; kc < 4; ++kc) {
            sh8 pf = *reinterpret_cast<const sh8*>(PsB[w] + lq * 128 + ((32 * kc + 16 * h) ^ qx));
            #pragma unroll
            for (int mt = 0; mt < 4; ++mt) {
                int dd = 32 * mt + lq;
                sh8 vf = *reinterpret_cast<const sh8*>(VsB + dd * 128 + ((32 * kc + 16 * h) ^ ((dd & 7) << 4)));
                acc[mt] = __builtin_amdgcn_mfma_f32_32x32x16_bf16(vf, pf, acc[mt], 0, 0, 0);
            }
        }
    }

    // ---- epilogue: 1/l, fused LN over d (lane-local + pair) + GELU ----
    float inv = 1.f / ll;
    float s1 = 0.f, s2 = 0.f;
    #pragma unroll
    for (int mt = 0; mt < 4; ++mt)
        #pragma unroll
        for (int e = 0; e < 16; ++e) {
            float v = acc[mt][e] * inv;
            acc[mt][e] = v;
            s1 += v; s2 += v * v;
        }
    s1 += __shfl_xor(s1, 32);
    s2 += __shfl_xor(s2, 32);
    float mean = s1 * (1.f / 128.f);
    float var  = s2 * (1.f / 128.f) - mean * mean;
    float rstd = rsqrtf(var + EPS);

    __syncthreads();   // everyone done reading K/V LDS
    float* Cb = (float*)(w ? VsB : KsB);   // wave-private 32x128 f32 staging
    #pragma unroll
    for (int mt = 0; mt < 4; ++mt)
        #pragma unroll
        for (int e = 0; e < 16; e += 2) {
            int d = (e & 3) + 8 * (e >> 2) + 4 * h + 32 * mt;
            float2 pr;
            pr.x = gelu_exact((acc[mt][e]     - mean) * rstd * g1s[d]     + b1s[d]);
            pr.y = gelu_exact((acc[mt][e + 1] - mean) * rstd * g1s[d + 1] + b1s[d + 1]);
            *reinterpret_cast<float2*>((char*)Cb + lq * 512 + ((d * 4) ^ qx)) = pr;
        }
    // wave-private: no barrier needed; compiler orders LDS ops
    float* cg = ctx + (size_t)(b * N_ + n0 + w * 32) * CO;
    #pragma unroll
    for (int rr = 0; rr < 4; ++rr) {
        int row = rr * 8 + (l >> 3);
        int cb0 = (l & 7) * 64;
        #pragma unroll
        for (int t = 0; t < 4; ++t) {
            float4 vv = *reinterpret_cast<const float4*>(
                (char*)Cb + row * 512 + ((cb0 + t * 16) ^ ((row & 7) << 4)));
            *reinterpret_cast<float4*>((char*)(cg + (size_t)row * CO) + cb0 + t * 16) = vv;
        }
    }
}

// ---------------- K4a: per-chunk partial sums for gate + BN stats ----------------
__global__ __launch_bounds__(128) void gate_part_kernel(
    const float* __restrict__ ctx, const float* __restrict__ Wca,
    float* __restrict__ Gp, float* __restrict__ S1p, float* __restrict__ S2p)
{
    const int ch = blockIdx.x;
    const int b  = blockIdx.y;
    const int c  = threadIdx.x;
    float g = 0, s1 = 0, s2 = 0;
    for (int i = 0; i < 98; ++i) {
        int n = ch * 98 + i;
        float vv = ctx[(size_t)(b * N_ + n) * CO + c];
        float w = Wca[n];
        g  = fmaf(vv, w, g);
        s1 += vv;
        s2 = fmaf(vv, vv, s2);
    }
    int idx = (ch * B_ + b) * CO + c;
    Gp[idx] = g; S1p[idx] = s1; S2p[idx] = s2;
}

// ---------------- K4c: finalize gate + BN stats ----------------
__global__ __launch_bounds__(128) void bn_stats_kernel(
    const float* __restrict__ Gp, const float* __restrict__ S1p, const float* __restrict__ S2p,
    const float* __restrict__ bca, float* __restrict__ Gate,
    float* __restrict__ mu, float* __restrict__ rstd)
{
    const int c = threadIdx.x;
    float msum = 0, sqsum = 0;
    for (int b = 0; b < B_; ++b) {
        float g = 0, s1 = 0, s2 = 0;
        for (int ch = 0; ch < 32; ++ch) {
            int idx = (ch * B_ + b) * CO + c;
            g += Gp[idx]; s1 += S1p[idx]; s2 += S2p[idx];
        }
        g += bca[0];
        Gate[b * CO + c] = g;
        msum  = fmaf(g, s1, msum);
        sqsum = fmaf(g * g, s2, sqsum);
    }
    float mean = msum * (1.f / 25088.f);
    float var  = sqsum * (1.f / 25088.f) - mean * mean;
    mu[c] = mean;
    rstd[c] = rsqrtf(var + EPS);
}

// ---------------- K5: transpose + gate + BN + GELU ----------------
__global__ __launch_bounds__(256) void out_kernel(
    const float* __restrict__ ctx, const float* __restrict__ Gate,
    const float* __restrict__ mu, const float* __restrict__ rstd,
    const float* __restrict__ bng, const float* __restrict__ bnb,
    float* __restrict__ out)
{
    __shared__ float T[32][33];
    const int nt = blockIdx.x, ct = blockIdx.y, b = blockIdx.z;
    const int n0 = nt * 32, c0 = ct * 32;
    const int tid = threadIdx.x;
    const int j = tid & 31, i0 = tid >> 5;
    #pragma unroll
    for (int p = 0; p < 4; ++p) {
        int i = i0 + p * 8;
        T[i][j] = ctx[(size_t)(b * N_ + n0 + i) * CO + c0 + j];
    }
    __syncthreads();
    #pragma unroll
    for (int p = 0; p < 4; ++p) {
        int cl = i0 + p * 8;
        int c = c0 + cl;
        float val = Gate[b * CO + c] * T[j][cl];
        val = (val - mu[c]) * rstd[c] * bng[c] + bnb[c];
        out[((size_t)(b * CO + c)) * N_ + n0 + j] = gelu_exact(val);
    }
}

extern "C" void kernel_launch(void* const* d_in, const int* in_sizes, int n_in,
                              void* d_out, int out_size, void* d_ws, size_t ws_size,
                              hipStream_t stream)
{
    const float* x   = (const float*)d_in[0];
    const float* Wq  = (const float*)d_in[1];
    const float* bq  = (const float*)d_in[2];
    const float* gq  = (const float*)d_in[3];
    const float* btq = (const float*)d_in[4];
    const float* Wk  = (const float*)d_in[5];
    const float* bk  = (const float*)d_in[6];
    const float* gk  = (const float*)d_in[7];
    const float* btk = (const float*)d_in[8];
    const float* Wv  = (const float*)d_in[9];
    const float* bv  = (const float*)d_in[10];
    const float* gv  = (const float*)d_in[11];
    const float* btv = (const float*)d_in[12];
    const float* g1  = (const float*)d_in[13];
    const float* b1  = (const float*)d_in[14];
    const float* Wca = (const float*)d_in[15];
    const float* bca = (const float*)d_in[16];
    const float* bng = (const float*)d_in[17];
    const float* bnb = (const float*)d_in[18];
    float* out = (float*)d_out;

    const size_t SZ = (size_t)B_ * N_ * CO;   // 3,211,264
    unsigned short* qb = (unsigned short*)d_ws;
    unsigned short* kb = qb + SZ;
    unsigned short* vt = kb + SZ;
    float* cb   = (float*)(vt + SZ);
    float* Gp   = cb + SZ;
    float* S1p  = Gp + 32768;
    float* S2p  = S1p + 32768;
    float* Gate = S2p + 32768;
    float* muv  = Gate + 1024;
    float* rsv  = muv + 128;

    qkv_kernel<<<dim3(98, 8), 256, 0, stream>>>(x, Wq, bq, gq, btq,
                                                Wk, bk, gk, btk,
                                                Wv, bv, gv, btv, qb, kb, vt);
    attn_kernel<<<dim3(49, 8), 128, 0, stream>>>(qb, kb, vt, g1, b1, cb);
    gate_part_kernel<<<dim3(32, 8), 128, 0, stream>>>(cb, Wca, Gp, S1p, S2p);
    bn_stats_kernel<<<dim3(1), 128, 0, stream>>>(Gp, S1p, S2p, bca, Gate, muv, rsv);
    out_kernel<<<dim3(98, 4, 8), 256, 0, stream>>>(cb, Gate, muv, rsv, bng, bnb, out);
}

// Round 3
// 289.948 us; speedup vs baseline: 7.0032x; 1.6784x over previous
//
#include <hip/hip_runtime.h>
#include <math.h>

#define B_   8
#define CIN  64
#define N_   3136
#define DIN  576
#define CO   128
#define EPS  1e-5f
#define QSCALE 0.0883883476483184f   // 1/sqrt(128)

typedef __attribute__((ext_vector_type(8))) short sh8;     // 8 bf16 (4 VGPRs)
typedef __attribute__((ext_vector_type(16))) float fx16;   // MFMA 32x32 accum

__device__ __forceinline__ float gelu_exact(float x) {
    return 0.5f * x * (1.0f + erff(x * 0.7071067811865475f));
}
__device__ __forceinline__ unsigned short f2bf(float f) {   // RN-even f32->bf16
    unsigned u = __float_as_uint(f);
    u += 0x7fffu + ((u >> 16) & 1u);
    return (unsigned short)(u >> 16);
}
__device__ __forceinline__ unsigned pack2(float a, float b) {
    return (unsigned)f2bf(a) | ((unsigned)f2bf(b) << 16);
}

// ---------------- K0: pack Wq|Wk|Wv -> pre-swizzled bf16 LDS image ----------------
// Image: 9 K-steps x [384 cols][64 k] bf16, byte-in-row XOR'd with (col&7)<<4.
__global__ __launch_bounds__(256) void wprep_kernel(
    const float* __restrict__ Wq, const float* __restrict__ Wk,
    const float* __restrict__ Wv, unsigned short* __restrict__ wimg)
{
    int id = blockIdx.x * 256 + threadIdx.x;          // 110592 u32 elements
    int col = id % 384;
    int k2  = id / 384;                               // 0..287
    int k   = 2 * k2;
    int s   = k >> 6;
    int kk  = k & 63;
    int t   = col >> 7, c = col & 127;
    const float* W = (t == 0) ? Wq : (t == 1) ? Wk : Wv;
    float v0 = W[(size_t)k * CO + c];
    float v1 = W[(size_t)(k + 1) * CO + c];
    char* dst = (char*)wimg + (size_t)s * 49152 + col * 128 + ((kk * 2) ^ ((col & 7) << 4));
    *reinterpret_cast<unsigned*>(dst) = pack2(v0, v1);
}

// ---------------- K1: im2col + QKV MFMA GEMM + bias + LayerNorm -> bf16 ----------------
// Block: 64 tokens x 384 cols (Q|K|V), 4 waves, K-loop 9 x 64.
__global__ __launch_bounds__(256, 2) void qkv_kernel(
    const float* __restrict__ x, const unsigned short* __restrict__ wimg,
    const float* __restrict__ bq, const float* __restrict__ gq, const float* __restrict__ btq,
    const float* __restrict__ bk, const float* __restrict__ gk, const float* __restrict__ btk,
    const float* __restrict__ bv, const float* __restrict__ gv, const float* __restrict__ btv,
    unsigned short* __restrict__ qo, unsigned short* __restrict__ ko,
    unsigned short* __restrict__ vt)
{
    __shared__ alignas(16) char Alds[8192];    // [64 rows][64 k] bf16, swizzled
    __shared__ alignas(16) char Wlds[49152];   // [384 cols][64 k] bf16, swizzled image
    const int b   = blockIdx.y;
    const int n0  = blockIdx.x * 64;
    const int tid = threadIdx.x;
    const int w   = tid >> 6;
    const int l   = tid & 63;
    const int h   = l >> 5;
    const int lq  = l & 31;
    const int key = (lq & 7) << 4;             // read swizzle (same for A and W)

    fx16 acc[2][3];
    #pragma unroll
    for (int mt = 0; mt < 2; ++mt)
        #pragma unroll
        for (int cb = 0; cb < 3; ++cb)
            #pragma unroll
            for (int e = 0; e < 16; ++e) acc[mt][cb][e] = 0.f;

    for (int s = 0; s < 9; ++s) {
        __syncthreads();
        // stage W tile (48KB) via linear global_load_lds from pre-swizzled image
        #pragma unroll
        for (int j = 0; j < 12; ++j) {
            int o = (w * 12 + j) * 1024;
            __builtin_amdgcn_global_load_lds(
                (const __attribute__((address_space(1))) void*)((const char*)wimg + (size_t)s * 49152 + o + l * 16),
                (__attribute__((address_space(3))) void*)(Wlds + o),
                16, 0, 0);
        }
        // stage A tile: im2col gather, reg-staged swizzled ds_write_b32
        #pragma unroll
        for (int i = 0; i < 8; ++i) {
            int k2 = w + 4 * i;                // 0..31
            int d  = s * 64 + 2 * k2;
            int n  = n0 + l;
            int oh = n / 56, ow = n - 56 * oh;
            int c0 = d / 9, r9 = d - 9 * c0;
            int kh0 = r9 / 3, kw0 = r9 - 3 * kh0;
            int ih0 = oh + kh0 - 1, iw0 = ow + kw0 - 1;
            float v0 = 0.f;
            if ((unsigned)ih0 < 56u && (unsigned)iw0 < 56u)
                v0 = x[((b * CIN + c0) * 56 + ih0) * 56 + iw0];
            int d1 = d + 1;
            int c1 = d1 / 9, r91 = d1 - 9 * c1;
            int kh1 = r91 / 3, kw1 = r91 - 3 * kh1;
            int ih1 = oh + kh1 - 1, iw1 = ow + kw1 - 1;
            float v1 = 0.f;
            if ((unsigned)ih1 < 56u && (unsigned)iw1 < 56u)
                v1 = x[((b * CIN + c1) * 56 + ih1) * 56 + iw1];
            *reinterpret_cast<unsigned*>(Alds + l * 128 + ((4 * k2) ^ ((l & 7) << 4))) = pack2(v0, v1);
        }
        asm volatile("s_waitcnt vmcnt(0)" ::: "memory");
        __syncthreads();

        #pragma unroll
        for (int kc = 0; kc < 4; ++kc) {
            int cb_in = (kc * 32 + h * 16);
            sh8 a0 = *reinterpret_cast<const sh8*>(Alds + lq * 128        + (cb_in ^ key));
            sh8 a1 = *reinterpret_cast<const sh8*>(Alds + (lq + 32) * 128 + (cb_in ^ key));
            #pragma unroll
            for (int cb = 0; cb < 3; ++cb) {
                int col = w * 96 + cb * 32 + lq;
                sh8 wf = *reinterpret_cast<const sh8*>(Wlds + col * 128 + (cb_in ^ key));
                acc[0][cb] = __builtin_amdgcn_mfma_f32_32x32x16_bf16(a0, wf, acc[0][cb], 0, 0, 0);
                acc[1][cb] = __builtin_amdgcn_mfma_f32_32x32x16_bf16(a1, wf, acc[1][cb], 0, 0, 0);
            }
        }
    }

    // ---- epilogue: per type, stage 64x128 fp32 to LDS, LN, write bf16 ----
    float* outT = (float*)Wlds;   // [64][132] fp32 = 33792 B
    const int rix = tid >> 3;
    const int sub = tid & 7;
    #pragma unroll
    for (int t = 0; t < 3; ++t) {
        const float* bias = (t == 0) ? bq : (t == 1) ? bk : bv;
        const float* gg   = (t == 0) ? gq : (t == 1) ? gk : gv;
        const float* bb   = (t == 0) ? btq : (t == 1) ? btk : btv;
        __syncthreads();
        #pragma unroll
        for (int cb = 0; cb < 3; ++cb) {
            if (((w * 96 + cb * 32) >> 7) == t) {
                int cl = w * 96 + cb * 32 + lq - t * 128;
                float bv_ = bias[cl];
                #pragma unroll
                for (int mt = 0; mt < 2; ++mt)
                    #pragma unroll
                    for (int e = 0; e < 16; ++e) {
                        int row = mt * 32 + (e & 3) + 8 * (e >> 2) + 4 * h;
                        outT[row * 132 + cl] = acc[mt][cb][e] + bv_;
                    }
            }
        }
        __syncthreads();
        #pragma unroll
        for (int rh = 0; rh < 2; ++rh) {
            int row = rh * 32 + rix;
            float s1 = 0.f, s2 = 0.f;
            #pragma unroll
            for (int u = 0; u < 16; ++u) {
                float vv = outT[row * 132 + sub * 16 + u];
                s1 += vv; s2 += vv * vv;
            }
            #pragma unroll
            for (int off = 1; off < 8; off <<= 1) {
                s1 += __shfl_xor(s1, off);
                s2 += __shfl_xor(s2, off);
            }
            float mean = s1 * (1.f / 128.f);
            float var  = s2 * (1.f / 128.f) - mean * mean;
            float rstd = rsqrtf(var + EPS);
            if (t < 2) {
                float extra = (t == 0) ? QSCALE : 1.f;
                unsigned short* op = (t == 0 ? qo : ko) + (size_t)(b * N_ + n0 + row) * CO;
                #pragma unroll
                for (int u4 = 0; u4 < 4; ++u4) {
                    int c = sub * 16 + u4 * 4;
                    ushort4 o4;
                    o4.x = f2bf(((outT[row * 132 + c + 0] - mean) * rstd * gg[c + 0] + bb[c + 0]) * extra);
                    o4.y = f2bf(((outT[row * 132 + c + 1] - mean) * rstd * gg[c + 1] + bb[c + 1]) * extra);
                    o4.z = f2bf(((outT[row * 132 + c + 2] - mean) * rstd * gg[c + 2] + bb[c + 2]) * extra);
                    o4.w = f2bf(((outT[row * 132 + c + 3] - mean) * rstd * gg[c + 3] + bb[c + 3]) * extra);
                    *reinterpret_cast<ushort4*>(&op[c]) = o4;
                }
            } else {
                #pragma unroll
                for (int u = 0; u < 16; ++u) {
                    int c = sub * 16 + u;
                    outT[row * 132 + c] = (outT[row * 132 + c] - mean) * rstd * gg[c] + bb[c];
                }
            }
        }
        if (t == 2) {
            __syncthreads();
            // transposed bf16 write V^T[b][c][n0..n0+63]
            int c = tid & 127, qs = tid >> 7;
            unsigned short* vp = vt + (size_t)(b * CO + c) * N_ + n0 + qs * 32;
            #pragma unroll
            for (int g4 = 0; g4 < 4; ++g4) {
                int r0 = qs * 32 + g4 * 8;
                uint4 wv;
                wv.x = pack2(outT[(r0 + 0) * 132 + c], outT[(r0 + 1) * 132 + c]);
                wv.y = pack2(outT[(r0 + 2) * 132 + c], outT[(r0 + 3) * 132 + c]);
                wv.z = pack2(outT[(r0 + 4) * 132 + c], outT[(r0 + 5) * 132 + c]);
                wv.w = pack2(outT[(r0 + 6) * 132 + c], outT[(r0 + 7) * 132 + c]);
                *reinterpret_cast<uint4*>(vp + g4 * 8) = wv;
            }
        }
    }
}

// ---------------- K2: MFMA flash attention + fused LN1 + GELU ----------------
__global__ __launch_bounds__(128, 2) void attn_kernel(
    const unsigned short* __restrict__ Qb, const unsigned short* __restrict__ Kb,
    const unsigned short* __restrict__ Vt, const float* __restrict__ g1,
    const float* __restrict__ b1, float* __restrict__ ctx)
{
    __shared__ alignas(16) char KsB[16384];      // K tile [64][128] bf16, swizzled
    __shared__ alignas(16) char VsB[16384];      // V^T tile [128][64] bf16, swizzled
    __shared__ alignas(16) char PsB[2][4096];    // per-wave P [32 q][64 kv] bf16, swizzled
    __shared__ float g1s[128], b1s[128];

    const int b   = blockIdx.y;
    const int n0  = blockIdx.x * 64;
    const int tid = threadIdx.x;
    const int w   = tid >> 6;
    const int l   = tid & 63;
    const int h   = l >> 5;
    const int lq  = l & 31;
    const int qx  = (lq & 7) << 4;

    if (tid < 128) { g1s[tid] = g1[tid]; b1s[tid] = b1[tid]; }

    sh8 qr[8];
    {
        const unsigned short* qp = Qb + (size_t)(b * N_ + n0 + w * 32 + lq) * CO + 8 * h;
        #pragma unroll
        for (int kc = 0; kc < 8; ++kc)
            qr[kc] = *reinterpret_cast<const sh8*>(qp + 16 * kc);
    }

    fx16 acc[4];
    #pragma unroll
    for (int mt = 0; mt < 4; ++mt)
        #pragma unroll
        for (int e = 0; e < 16; ++e) acc[mt][e] = 0.f;
    float m = -1e30f, ll = 0.f;

    const char* kgb = (const char*)(Kb + (size_t)b * N_ * CO);
    const char* vgb = (const char*)(Vt + (size_t)b * CO * N_);

    for (int kt = 0; kt < 49; ++kt) {
        const int kb = kt * 64;
        __syncthreads();
        #pragma unroll
        for (int j = 0; j < 8; ++j) {
            int o   = (w * 8 + j) * 1024 + l * 16;
            int row = o >> 8;
            int cc  = (o & 255) ^ ((row & 15) << 4);
            const char* src = kgb + (size_t)(kb + row) * 256 + cc;
            __builtin_amdgcn_global_load_lds(
                (const __attribute__((address_space(1))) void*)src,
                (__attribute__((address_space(3))) void*)(KsB + (w * 8 + j) * 1024),
                16, 0, 0);
        }
        #pragma unroll
        for (int j = 0; j < 8; ++j) {
            int o  = (w * 8 + j) * 1024 + l * 16;
            int d  = o >> 7;
            int cc = (o & 127) ^ ((d & 7) << 4);
            const char* src = vgb + ((size_t)d * N_ + kb) * 2 + cc;
            __builtin_amdgcn_global_load_lds(
                (const __attribute__((address_space(1))) void*)src,
                (__attribute__((address_space(3))) void*)(VsB + (w * 8 + j) * 1024),
                16, 0, 0);
        }
        asm volatile("s_waitcnt vmcnt(0)" ::: "memory");
        __syncthreads();

        fx16 s[2];
        #pragma unroll
        for (int f = 0; f < 2; ++f)
            #pragma unroll
            for (int e = 0; e < 16; ++e) s[f][e] = 0.f;
        #pragma unroll
        for (int kc = 0; kc < 8; ++kc) {
            int cb = 32 * kc + 16 * h;
            sh8 a0 = *reinterpret_cast<const sh8*>(KsB + (lq       * 256 + (cb ^ ((lq & 15) << 4))));
            sh8 a1 = *reinterpret_cast<const sh8*>(KsB + ((lq + 32) * 256 + (cb ^ (((lq + 32) & 15) << 4))));
            s[0] = __builtin_amdgcn_mfma_f32_32x32x16_bf16(a0, qr[kc], s[0], 0, 0, 0);
            s[1] = __builtin_amdgcn_mfma_f32_32x32x16_bf16(a1, qr[kc], s[1], 0, 0, 0);
        }

        float pm = -1e30f;
        #pragma unroll
        for (int f = 0; f < 2; ++f)
            #pragma unroll
            for (int e = 0; e < 16; ++e) pm = fmaxf(pm, s[f][e]);
        pm = fmaxf(pm, __shfl_xor(pm, 32));
        float mn = fmaxf(m, pm);
        float sc = __expf(m - mn);
        float p[2][16];
        float rs = 0.f;
        #pragma unroll
        for (int f = 0; f < 2; ++f)
            #pragma unroll
            for (int e = 0; e < 16; ++e) {
                float pe = __expf(s[f][e] - mn);
                p[f][e] = pe; rs += pe;
            }
        rs += __shfl_xor(rs, 32);
        ll = ll * sc + rs;
        m = mn;
        #pragma unroll
        for (int mt = 0; mt < 4; ++mt)
            #pragma unroll
            for (int e = 0; e < 16; ++e) acc[mt][e] *= sc;

        {
            char* pw = PsB[w] + lq * 128;
            #pragma unroll
            for (int f = 0; f < 2; ++f)
                #pragma unroll
                for (int j = 0; j < 4; ++j) {
                    uint2 wv;
                    wv.x = pack2(p[f][4 * j + 0], p[f][4 * j + 1]);
                    wv.y = pack2(p[f][4 * j + 2], p[f][4 * j + 3]);
                    *reinterpret_cast<uint2*>(pw + ((64 * f + 16 * j + 8 * h) ^ qx)) = wv;
                }
        }

        #pragma unroll
        for (int kc = 0; kc < 4; ++kc) {
            sh8 pf = *reinterpret_cast<const sh8*>(PsB[w] + lq * 128 + ((32 * kc + 16 * h) ^ qx));
            #pragma unroll
            for (int mt = 0; mt < 4; ++mt) {
                int dd = 32 * mt + lq;
                sh8 vf = *reinterpret_cast<const sh8*>(VsB + dd * 128 + ((32 * kc + 16 * h) ^ ((dd & 7) << 4)));
                acc[mt] = __builtin_amdgcn_mfma_f32_32x32x16_bf16(vf, pf, acc[mt], 0, 0, 0);
            }
        }
    }

    float inv = 1.f / ll;
    float s1 = 0.f, s2 = 0.f;
    #pragma unroll
    for (int mt = 0; mt < 4; ++mt)
        #pragma unroll
        for (int e = 0; e < 16; ++e) {
            float v = acc[mt][e] * inv;
            acc[mt][e] = v;
            s1 += v; s2 += v * v;
        }
    s1 += __shfl_xor(s1, 32);
    s2 += __shfl_xor(s2, 32);
    float mean = s1 * (1.f / 128.f);
    float var  = s2 * (1.f / 128.f) - mean * mean;
    float rstd = rsqrtf(var + EPS);

    __syncthreads();
    float* Cb = (float*)(w ? VsB : KsB);
    #pragma unroll
    for (int mt = 0; mt < 4; ++mt)
        #pragma unroll
        for (int e = 0; e < 16; e += 2) {
            int d = (e & 3) + 8 * (e >> 2) + 4 * h + 32 * mt;
            float2 pr;
            pr.x = gelu_exact((acc[mt][e]     - mean) * rstd * g1s[d]     + b1s[d]);
            pr.y = gelu_exact((acc[mt][e + 1] - mean) * rstd * g1s[d + 1] + b1s[d + 1]);
            *reinterpret_cast<float2*>((char*)Cb + lq * 512 + ((d * 4) ^ qx)) = pr;
        }
    float* cg = ctx + (size_t)(b * N_ + n0 + w * 32) * CO;
    #pragma unroll
    for (int rr = 0; rr < 4; ++rr) {
        int row = rr * 8 + (l >> 3);
        int cb0 = (l & 7) * 64;
        #pragma unroll
        for (int t = 0; t < 4; ++t) {
            float4 vv = *reinterpret_cast<const float4*>(
                (char*)Cb + row * 512 + ((cb0 + t * 16) ^ ((row & 7) << 4)));
            *reinterpret_cast<float4*>((char*)(cg + (size_t)row * CO) + cb0 + t * 16) = vv;
        }
    }
}

// ---------------- K4a: per-chunk partial sums for gate + BN stats ----------------
__global__ __launch_bounds__(128) void gate_part_kernel(
    const float* __restrict__ ctx, const float* __restrict__ Wca,
    float* __restrict__ Gp, float* __restrict__ S1p, float* __restrict__ S2p)
{
    const int ch = blockIdx.x;
    const int b  = blockIdx.y;
    const int c  = threadIdx.x;
    float g = 0, s1 = 0, s2 = 0;
    for (int i = 0; i < 98; ++i) {
        int n = ch * 98 + i;
        float vv = ctx[(size_t)(b * N_ + n) * CO + c];
        float w = Wca[n];
        g  = fmaf(vv, w, g);
        s1 += vv;
        s2 = fmaf(vv, vv, s2);
    }
    int idx = (ch * B_ + b) * CO + c;
    Gp[idx] = g; S1p[idx] = s1; S2p[idx] = s2;
}

// ---------------- K4c: finalize gate + BN stats ----------------
__global__ __launch_bounds__(128) void bn_stats_kernel(
    const float* __restrict__ Gp, const float* __restrict__ S1p, const float* __restrict__ S2p,
    const float* __restrict__ bca, float* __restrict__ Gate,
    float* __restrict__ mu, float* __restrict__ rstd)
{
    const int c = threadIdx.x;
    float msum = 0, sqsum = 0;
    for (int b = 0; b < B_; ++b) {
        float g = 0, s1 = 0, s2 = 0;
        for (int ch = 0; ch < 32; ++ch) {
            int idx = (ch * B_ + b) * CO + c;
            g += Gp[idx]; s1 += S1p[idx]; s2 += S2p[idx];
        }
        g += bca[0];
        Gate[b * CO + c] = g;
        msum  = fmaf(g, s1, msum);
        sqsum = fmaf(g * g, s2, sqsum);
    }
    float mean = msum * (1.f / 25088.f);
    float var  = sqsum * (1.f / 25088.f) - mean * mean;
    mu[c] = mean;
    rstd[c] = rsqrtf(var + EPS);
}

// ---------------- K5: transpose + gate + BN + GELU ----------------
__global__ __launch_bounds__(256) void out_kernel(
    const float* __restrict__ ctx, const float* __restrict__ Gate,
    const float* __restrict__ mu, const float* __restrict__ rstd,
    const float* __restrict__ bng, const float* __restrict__ bnb,
    float* __restrict__ out)
{
    __shared__ float T[32][33];
    const int nt = blockIdx.x, ct = blockIdx.y, b = blockIdx.z;
    const int n0 = nt * 32, c0 = ct * 32;
    const int tid = threadIdx.x;
    const int j = tid & 31, i0 = tid >> 5;
    #pragma unroll
    for (int p = 0; p < 4; ++p) {
        int i = i0 + p * 8;
        T[i][j] = ctx[(size_t)(b * N_ + n0 + i) * CO + c0 + j];
    }
    __syncthreads();
    #pragma unroll
    for (int p = 0; p < 4; ++p) {
        int cl = i0 + p * 8;
        int c = c0 + cl;
        float val = Gate[b * CO + c] * T[j][cl];
        val = (val - mu[c]) * rstd[c] * bng[c] + bnb[c];
        out[((size_t)(b * CO + c)) * N_ + n0 + j] = gelu_exact(val);
    }
}

extern "C" void kernel_launch(void* const* d_in, const int* in_sizes, int n_in,
                              void* d_out, int out_size, void* d_ws, size_t ws_size,
                              hipStream_t stream)
{
    const float* x   = (const float*)d_in[0];
    const float* Wq  = (const float*)d_in[1];
    const float* bq  = (const float*)d_in[2];
    const float* gq  = (const float*)d_in[3];
    const float* btq = (const float*)d_in[4];
    const float* Wk  = (const float*)d_in[5];
    const float* bk  = (const float*)d_in[6];
    const float* gk  = (const float*)d_in[7];
    const float* btk = (const float*)d_in[8];
    const float* Wv  = (const float*)d_in[9];
    const float* bv  = (const float*)d_in[10];
    const float* gv  = (const float*)d_in[11];
    const float* btv = (const float*)d_in[12];
    const float* g1  = (const float*)d_in[13];
    const float* b1  = (const float*)d_in[14];
    const float* Wca = (const float*)d_in[15];
    const float* bca = (const float*)d_in[16];
    const float* bng = (const float*)d_in[17];
    const float* bnb = (const float*)d_in[18];
    float* out = (float*)d_out;

    const size_t SZ = (size_t)B_ * N_ * CO;   // 3,211,264
    unsigned short* qb = (unsigned short*)d_ws;
    unsigned short* kb = qb + SZ;
    unsigned short* vt = kb + SZ;
    float* cb   = (float*)(vt + SZ);
    float* Gp   = cb + SZ;
    float* S1p  = Gp + 32768;
    float* S2p  = S1p + 32768;
    float* Gate = S2p + 32768;
    float* muv  = Gate + 1024;
    float* rsv  = muv + 128;
    unsigned short* wimg = (unsigned short*)(rsv + 128);   // 442,368 B

    wprep_kernel<<<dim3(432), 256, 0, stream>>>(Wq, Wk, Wv, wimg);
    qkv_kernel<<<dim3(49, 8), 256, 0, stream>>>(x, wimg,
                                                bq, gq, btq, bk, gk, btk, bv, gv, btv,
                                                qb, kb, vt);
    attn_kernel<<<dim3(49, 8), 128, 0, stream>>>(qb, kb, vt, g1, b1, cb);
    gate_part_kernel<<<dim3(32, 8), 128, 0, stream>>>(cb, Wca, Gp, S1p, S2p);
    bn_stats_kernel<<<dim3(1), 128, 0, stream>>>(Gp, S1p, S2p, bca, Gate, muv, rsv);
    out_kernel<<<dim3(98, 4, 8), 256, 0, stream>>>(cb, Gate, muv, rsv, bng, bnb, out);
}

// Round 4
// 242.645 us; speedup vs baseline: 8.3684x; 1.1949x over previous
//
#include <hip/hip_runtime.h>
#include <math.h>

#define B_   8
#define CIN  64
#define N_   3136
#define DIN  576
#define CO   128
#define EPS  1e-5f
#define QSCALE 0.0883883476483184f   // 1/sqrt(128)

typedef __attribute__((ext_vector_type(8))) short sh8;     // 8 bf16 (4 VGPRs)
typedef __attribute__((ext_vector_type(16))) float fx16;   // MFMA 32x32 accum

__device__ __forceinline__ float gelu_exact(float x) {
    return 0.5f * x * (1.0f + erff(x * 0.7071067811865475f));
}
__device__ __forceinline__ unsigned short f2bf(float f) {   // RN-even f32->bf16
    unsigned u = __float_as_uint(f);
    u += 0x7fffu + ((u >> 16) & 1u);
    return (unsigned short)(u >> 16);
}
__device__ __forceinline__ unsigned pack2(float a, float b) {
    return (unsigned)f2bf(a) | ((unsigned)f2bf(b) << 16);
}

// ---------------- K0: pack Wq|Wk|Wv -> pre-swizzled bf16 LDS image ----------------
__global__ __launch_bounds__(256) void wprep_kernel(
    const float* __restrict__ Wq, const float* __restrict__ Wk,
    const float* __restrict__ Wv, unsigned short* __restrict__ wimg)
{
    int id = blockIdx.x * 256 + threadIdx.x;          // 110592 u32 elements
    int col = id % 384;
    int k2  = id / 384;                               // 0..287
    int k   = 2 * k2;
    int s   = k >> 6;
    int kk  = k & 63;
    int t   = col >> 7, c = col & 127;
    const float* W = (t == 0) ? Wq : (t == 1) ? Wk : Wv;
    float v0 = W[(size_t)k * CO + c];
    float v1 = W[(size_t)(k + 1) * CO + c];
    char* dst = (char*)wimg + (size_t)s * 49152 + col * 128 + ((kk * 2) ^ ((col & 7) << 4));
    *reinterpret_cast<unsigned*>(dst) = pack2(v0, v1);
}

// ---------------- K1: im2col + QKV MFMA GEMM + bias + LayerNorm -> bf16 ----------------
__global__ __launch_bounds__(256, 2) void qkv_kernel(
    const float* __restrict__ x, const unsigned short* __restrict__ wimg,
    const float* __restrict__ bq, const float* __restrict__ gq, const float* __restrict__ btq,
    const float* __restrict__ bk, const float* __restrict__ gk, const float* __restrict__ btk,
    const float* __restrict__ bv, const float* __restrict__ gv, const float* __restrict__ btv,
    unsigned short* __restrict__ qo, unsigned short* __restrict__ ko,
    unsigned short* __restrict__ vt)
{
    __shared__ alignas(16) char Alds[8192];    // [64 rows][64 k] bf16, swizzled
    __shared__ alignas(16) char Wlds[49152];   // [384 cols][64 k] bf16, swizzled image
    const int b   = blockIdx.y;
    const int n0  = blockIdx.x * 64;
    const int tid = threadIdx.x;
    const int w   = tid >> 6;
    const int l   = tid & 63;
    const int h   = l >> 5;
    const int lq  = l & 31;
    const int key = (lq & 7) << 4;

    fx16 acc[2][3];
    #pragma unroll
    for (int mt = 0; mt < 2; ++mt)
        #pragma unroll
        for (int cb = 0; cb < 3; ++cb)
            #pragma unroll
            for (int e = 0; e < 16; ++e) acc[mt][cb][e] = 0.f;

    for (int s = 0; s < 9; ++s) {
        __syncthreads();
        #pragma unroll
        for (int j = 0; j < 12; ++j) {
            int o = (w * 12 + j) * 1024;
            __builtin_amdgcn_global_load_lds(
                (const __attribute__((address_space(1))) void*)((const char*)wimg + (size_t)s * 49152 + o + l * 16),
                (__attribute__((address_space(3))) void*)(Wlds + o),
                16, 0, 0);
        }
        #pragma unroll
        for (int i = 0; i < 8; ++i) {
            int k2 = w + 4 * i;                // 0..31
            int d  = s * 64 + 2 * k2;
            int n  = n0 + l;
            int oh = n / 56, ow = n - 56 * oh;
            int c0 = d / 9, r9 = d - 9 * c0;
            int kh0 = r9 / 3, kw0 = r9 - 3 * kh0;
            int ih0 = oh + kh0 - 1, iw0 = ow + kw0 - 1;
            float v0 = 0.f;
            if ((unsigned)ih0 < 56u && (unsigned)iw0 < 56u)
                v0 = x[((b * CIN + c0) * 56 + ih0) * 56 + iw0];
            int d1 = d + 1;
            int c1 = d1 / 9, r91 = d1 - 9 * c1;
            int kh1 = r91 / 3, kw1 = r91 - 3 * kh1;
            int ih1 = oh + kh1 - 1, iw1 = ow + kw1 - 1;
            float v1 = 0.f;
            if ((unsigned)ih1 < 56u && (unsigned)iw1 < 56u)
                v1 = x[((b * CIN + c1) * 56 + ih1) * 56 + iw1];
            *reinterpret_cast<unsigned*>(Alds + l * 128 + ((4 * k2) ^ ((l & 7) << 4))) = pack2(v0, v1);
        }
        asm volatile("s_waitcnt vmcnt(0)" ::: "memory");
        __syncthreads();

        #pragma unroll
        for (int kc = 0; kc < 4; ++kc) {
            int cb_in = (kc * 32 + h * 16);
            sh8 a0 = *reinterpret_cast<const sh8*>(Alds + lq * 128        + (cb_in ^ key));
            sh8 a1 = *reinterpret_cast<const sh8*>(Alds + (lq + 32) * 128 + (cb_in ^ key));
            #pragma unroll
            for (int cb = 0; cb < 3; ++cb) {
                int col = w * 96 + cb * 32 + lq;
                sh8 wf = *reinterpret_cast<const sh8*>(Wlds + col * 128 + (cb_in ^ key));
                acc[0][cb] = __builtin_amdgcn_mfma_f32_32x32x16_bf16(a0, wf, acc[0][cb], 0, 0, 0);
                acc[1][cb] = __builtin_amdgcn_mfma_f32_32x32x16_bf16(a1, wf, acc[1][cb], 0, 0, 0);
            }
        }
    }

    float* outT = (float*)Wlds;   // [64][132] fp32
    const int rix = tid >> 3;
    const int sub = tid & 7;
    #pragma unroll
    for (int t = 0; t < 3; ++t) {
        const float* bias = (t == 0) ? bq : (t == 1) ? bk : bv;
        const float* gg   = (t == 0) ? gq : (t == 1) ? gk : gv;
        const float* bb   = (t == 0) ? btq : (t == 1) ? btk : btv;
        __syncthreads();
        #pragma unroll
        for (int cb = 0; cb < 3; ++cb) {
            if (((w * 96 + cb * 32) >> 7) == t) {
                int cl = w * 96 + cb * 32 + lq - t * 128;
                float bv_ = bias[cl];
                #pragma unroll
                for (int mt = 0; mt < 2; ++mt)
                    #pragma unroll
                    for (int e = 0; e < 16; ++e) {
                        int row = mt * 32 + (e & 3) + 8 * (e >> 2) + 4 * h;
                        outT[row * 132 + cl] = acc[mt][cb][e] + bv_;
                    }
            }
        }
        __syncthreads();
        #pragma unroll
        for (int rh = 0; rh < 2; ++rh) {
            int row = rh * 32 + rix;
            float s1 = 0.f, s2 = 0.f;
            #pragma unroll
            for (int u = 0; u < 16; ++u) {
                float vv = outT[row * 132 + sub * 16 + u];
                s1 += vv; s2 += vv * vv;
            }
            #pragma unroll
            for (int off = 1; off < 8; off <<= 1) {
                s1 += __shfl_xor(s1, off);
                s2 += __shfl_xor(s2, off);
            }
            float mean = s1 * (1.f / 128.f);
            float var  = s2 * (1.f / 128.f) - mean * mean;
            float rstd = rsqrtf(var + EPS);
            if (t < 2) {
                float extra = (t == 0) ? QSCALE : 1.f;
                unsigned short* op = (t == 0 ? qo : ko) + (size_t)(b * N_ + n0 + row) * CO;
                #pragma unroll
                for (int u4 = 0; u4 < 4; ++u4) {
                    int c = sub * 16 + u4 * 4;
                    ushort4 o4;
                    o4.x = f2bf(((outT[row * 132 + c + 0] - mean) * rstd * gg[c + 0] + bb[c + 0]) * extra);
                    o4.y = f2bf(((outT[row * 132 + c + 1] - mean) * rstd * gg[c + 1] + bb[c + 1]) * extra);
                    o4.z = f2bf(((outT[row * 132 + c + 2] - mean) * rstd * gg[c + 2] + bb[c + 2]) * extra);
                    o4.w = f2bf(((outT[row * 132 + c + 3] - mean) * rstd * gg[c + 3] + bb[c + 3]) * extra);
                    *reinterpret_cast<ushort4*>(&op[c]) = o4;
                }
            } else {
                #pragma unroll
                for (int u = 0; u < 16; ++u) {
                    int c = sub * 16 + u;
                    outT[row * 132 + c] = (outT[row * 132 + c] - mean) * rstd * gg[c] + bb[c];
                }
            }
        }
        if (t == 2) {
            __syncthreads();
            int c = tid & 127, qs = tid >> 7;
            unsigned short* vp = vt + (size_t)(b * CO + c) * N_ + n0 + qs * 32;
            #pragma unroll
            for (int g4 = 0; g4 < 4; ++g4) {
                int r0 = qs * 32 + g4 * 8;
                uint4 wv;
                wv.x = pack2(outT[(r0 + 0) * 132 + c], outT[(r0 + 1) * 132 + c]);
                wv.y = pack2(outT[(r0 + 2) * 132 + c], outT[(r0 + 3) * 132 + c]);
                wv.z = pack2(outT[(r0 + 4) * 132 + c], outT[(r0 + 5) * 132 + c]);
                wv.w = pack2(outT[(r0 + 6) * 132 + c], outT[(r0 + 7) * 132 + c]);
                *reinterpret_cast<uint4*>(vp + g4 * 8) = wv;
            }
        }
    }
}

// ---------------- K2: MFMA flash attention, in-block KV-split, fused LN1+GELU ----------------
// 4 waves: waves {0,1} even KV tiles, {2,3} odd KV tiles; q-half = w&1.
// LDS map (81920 B): [0,16K) K0 | [16K,32K) V0 | [32K,48K) K1 | [48K,64K) V1 |
//                    [64K,80K) P[4 waves][4K].  Post-loop reuse:
//                    merge acc: [0,32K); ml: 64K; g1s/b1s: 64K+1K; epilogue stage: [32K,64K).
__global__ __launch_bounds__(256, 2) void attn_kernel(
    const unsigned short* __restrict__ Qb, const unsigned short* __restrict__ Kb,
    const unsigned short* __restrict__ Vt, const float* __restrict__ g1,
    const float* __restrict__ b1, float* __restrict__ ctx)
{
    __shared__ alignas(16) char LDS[81920];

    const int b   = blockIdx.y;
    const int n0  = blockIdx.x * 64;
    const int tid = threadIdx.x;
    const int w   = tid >> 6;
    const int l   = tid & 63;
    const int h   = l >> 5;
    const int lq  = l & 31;
    const int qh  = w & 1;     // q-row half
    const int grp = w >> 1;    // KV tile parity group
    const int qx  = (lq & 7) << 4;

    char* Kbase = LDS + grp * 32768;
    char* Vbase = Kbase + 16384;
    char* Pw    = LDS + 65536 + w * 4096;

    sh8 qr[8];
    {
        const unsigned short* qp = Qb + (size_t)(b * N_ + n0 + qh * 32 + lq) * CO + 8 * h;
        #pragma unroll
        for (int kc = 0; kc < 8; ++kc)
            qr[kc] = *reinterpret_cast<const sh8*>(qp + 16 * kc);
    }

    fx16 acc[4];
    #pragma unroll
    for (int mt = 0; mt < 4; ++mt)
        #pragma unroll
        for (int e = 0; e < 16; ++e) acc[mt][e] = 0.f;
    float m = -1e30f, ll = 0.f;

    const char* kgb = (const char*)(Kb + (size_t)b * N_ * CO);
    const char* vgb = (const char*)(Vt + (size_t)b * CO * N_);

    for (int it = 0; it < 25; ++it) {
        const int kb_e = (2 * it) * 64;
        const int kb_o = kb_e + 64;
        const bool has_odd = (it < 24);
        __syncthreads();   // previous tiles fully consumed
        // ---- stage K_e, V_e (and K_o, V_o): each wave 4 chunks of each ----
        #pragma unroll
        for (int j = 0; j < 4; ++j) {
            int cj = w * 4 + j;                    // 0..15
            int o  = cj * 1024 + l * 16;
            { // K even
                int row = o >> 8;
                int cc  = (o & 255) ^ ((row & 15) << 4);
                __builtin_amdgcn_global_load_lds(
                    (const __attribute__((address_space(1))) void*)(kgb + (size_t)(kb_e + row) * 256 + cc),
                    (__attribute__((address_space(3))) void*)(LDS + cj * 1024),
                    16, 0, 0);
            }
            { // V even
                int d  = o >> 7;
                int cc = (o & 127) ^ ((d & 7) << 4);
                __builtin_amdgcn_global_load_lds(
                    (const __attribute__((address_space(1))) void*)(vgb + ((size_t)d * N_ + kb_e) * 2 + cc),
                    (__attribute__((address_space(3))) void*)(LDS + 16384 + cj * 1024),
                    16, 0, 0);
            }
            if (has_odd) {
                { // K odd
                    int row = o >> 8;
                    int cc  = (o & 255) ^ ((row & 15) << 4);
                    __builtin_amdgcn_global_load_lds(
                        (const __attribute__((address_space(1))) void*)(kgb + (size_t)(kb_o + row) * 256 + cc),
                        (__attribute__((address_space(3))) void*)(LDS + 32768 + cj * 1024),
                        16, 0, 0);
                }
                { // V odd
                    int d  = o >> 7;
                    int cc = (o & 127) ^ ((d & 7) << 4);
                    __builtin_amdgcn_global_load_lds(
                        (const __attribute__((address_space(1))) void*)(vgb + ((size_t)d * N_ + kb_o) * 2 + cc),
                        (__attribute__((address_space(3))) void*)(LDS + 49152 + cj * 1024),
                        16, 0, 0);
                }
            }
        }
        asm volatile("s_waitcnt vmcnt(0)" ::: "memory");
        __syncthreads();

        const int t = 2 * it + grp;
        if (t <= 48) {
            // ---- QK^T (swapped): S^T[kv][q] ----
            fx16 s[2];
            #pragma unroll
            for (int f = 0; f < 2; ++f)
                #pragma unroll
                for (int e = 0; e < 16; ++e) s[f][e] = 0.f;
            #pragma unroll
            for (int kc = 0; kc < 8; ++kc) {
                int cb = 32 * kc + 16 * h;
                sh8 a0 = *reinterpret_cast<const sh8*>(Kbase + (lq       * 256 + (cb ^ ((lq & 15) << 4))));
                sh8 a1 = *reinterpret_cast<const sh8*>(Kbase + ((lq + 32) * 256 + (cb ^ (((lq + 32) & 15) << 4))));
                s[0] = __builtin_amdgcn_mfma_f32_32x32x16_bf16(a0, qr[kc], s[0], 0, 0, 0);
                s[1] = __builtin_amdgcn_mfma_f32_32x32x16_bf16(a1, qr[kc], s[1], 0, 0, 0);
            }

            float pm = -1e30f;
            #pragma unroll
            for (int f = 0; f < 2; ++f)
                #pragma unroll
                for (int e = 0; e < 16; ++e) pm = fmaxf(pm, s[f][e]);
            pm = fmaxf(pm, __shfl_xor(pm, 32));
            float mn = fmaxf(m, pm);
            float sc = __expf(m - mn);
            float p[2][16];
            float rs = 0.f;
            #pragma unroll
            for (int f = 0; f < 2; ++f)
                #pragma unroll
                for (int e = 0; e < 16; ++e) {
                    float pe = __expf(s[f][e] - mn);
                    p[f][e] = pe; rs += pe;
                }
            rs += __shfl_xor(rs, 32);
            ll = ll * sc + rs;
            m = mn;
            #pragma unroll
            for (int mt = 0; mt < 4; ++mt)
                #pragma unroll
                for (int e = 0; e < 16; ++e) acc[mt][e] *= sc;

            {
                char* pw = Pw + lq * 128;
                #pragma unroll
                for (int f = 0; f < 2; ++f)
                    #pragma unroll
                    for (int j = 0; j < 4; ++j) {
                        uint2 wv;
                        wv.x = pack2(p[f][4 * j + 0], p[f][4 * j + 1]);
                        wv.y = pack2(p[f][4 * j + 2], p[f][4 * j + 3]);
                        *reinterpret_cast<uint2*>(pw + ((64 * f + 16 * j + 8 * h) ^ qx)) = wv;
                    }
            }

            #pragma unroll
            for (int kc = 0; kc < 4; ++kc) {
                sh8 pf = *reinterpret_cast<const sh8*>(Pw + lq * 128 + ((32 * kc + 16 * h) ^ qx));
                #pragma unroll
                for (int mt = 0; mt < 4; ++mt) {
                    int dd = 32 * mt + lq;
                    sh8 vf = *reinterpret_cast<const sh8*>(Vbase + dd * 128 + ((32 * kc + 16 * h) ^ ((dd & 7) << 4)));
                    acc[mt] = __builtin_amdgcn_mfma_f32_32x32x16_bf16(vf, pf, acc[mt], 0, 0, 0);
                }
            }
        }
    }

    // ---- merge the two KV-parity partials (waves w and w^2) ----
    __syncthreads();
    float* ml  = (float*)(LDS + 65536);
    float* g1s = (float*)(LDS + 65536 + 1024);
    float* b1s = g1s + 128;
    if (h == 0) { ml[w * 32 + lq] = m; ml[128 + w * 32 + lq] = ll; }
    if (tid < 128) { g1s[tid] = g1[tid]; b1s[tid] = b1[tid]; }
    __syncthreads();
    float m_o = ml[(w ^ 2) * 32 + lq];
    float l_o = ml[128 + (w ^ 2) * 32 + lq];
    float mstar = fmaxf(m, m_o);
    float cs = __expf(m - mstar);
    if (w >= 2) {
        float2* dst = (float2*)(LDS + (w - 2) * 16384);
        #pragma unroll
        for (int mt = 0; mt < 4; ++mt)
            #pragma unroll
            for (int e2 = 0; e2 < 8; ++e2)
                dst[(mt * 8 + e2) * 64 + l] =
                    make_float2(cs * acc[mt][2 * e2], cs * acc[mt][2 * e2 + 1]);
    }
    __syncthreads();
    if (w < 2) {
        float lf = cs * ll + __expf(m_o - mstar) * l_o;
        const float2* src = (const float2*)(LDS + w * 16384);
        #pragma unroll
        for (int mt = 0; mt < 4; ++mt)
            #pragma unroll
            for (int e2 = 0; e2 < 8; ++e2) {
                float2 v = src[(mt * 8 + e2) * 64 + l];
                acc[mt][2 * e2]     = cs * acc[mt][2 * e2]     + v.x;
                acc[mt][2 * e2 + 1] = cs * acc[mt][2 * e2 + 1] + v.y;
            }

        // ---- epilogue: 1/l, fused LN over d + GELU ----
        float inv = 1.f / lf;
        float s1 = 0.f, s2 = 0.f;
        #pragma unroll
        for (int mt = 0; mt < 4; ++mt)
            #pragma unroll
            for (int e = 0; e < 16; ++e) {
                float v = acc[mt][e] * inv;
                acc[mt][e] = v;
                s1 += v; s2 += v * v;
            }
        s1 += __shfl_xor(s1, 32);
        s2 += __shfl_xor(s2, 32);
        float mean = s1 * (1.f / 128.f);
        float var  = s2 * (1.f / 128.f) - mean * mean;
        float rstd = rsqrtf(var + EPS);

        char* Cb = LDS + 32768 + qh * 16384;   // wave-private 32x128 f32 staging
        #pragma unroll
        for (int mt = 0; mt < 4; ++mt)
            #pragma unroll
            for (int e = 0; e < 16; e += 2) {
                int d = (e & 3) + 8 * (e >> 2) + 4 * h + 32 * mt;
                float2 pr;
                pr.x = gelu_exact((acc[mt][e]     - mean) * rstd * g1s[d]     + b1s[d]);
                pr.y = gelu_exact((acc[mt][e + 1] - mean) * rstd * g1s[d + 1] + b1s[d + 1]);
                *reinterpret_cast<float2*>(Cb + lq * 512 + ((d * 4) ^ qx)) = pr;
            }
        float* cg = ctx + (size_t)(b * N_ + n0 + qh * 32) * CO;
        #pragma unroll
        for (int rr = 0; rr < 4; ++rr) {
            int row = rr * 8 + (l >> 3);
            int cb0 = (l & 7) * 64;
            #pragma unroll
            for (int t = 0; t < 4; ++t) {
                float4 vv = *reinterpret_cast<const float4*>(
                    Cb + row * 512 + ((cb0 + t * 16) ^ ((row & 7) << 4)));
                *reinterpret_cast<float4*>((char*)(cg + (size_t)row * CO) + cb0 + t * 16) = vv;
            }
        }
    }
}

// ---------------- K4a: per-chunk partial sums for gate + BN stats ----------------
__global__ __launch_bounds__(128) void gate_part_kernel(
    const float* __restrict__ ctx, const float* __restrict__ Wca,
    float* __restrict__ Gp, float* __restrict__ S1p, float* __restrict__ S2p)
{
    const int ch = blockIdx.x;
    const int b  = blockIdx.y;
    const int c  = threadIdx.x;
    float g = 0, s1 = 0, s2 = 0;
    for (int i = 0; i < 98; ++i) {
        int n = ch * 98 + i;
        float vv = ctx[(size_t)(b * N_ + n) * CO + c];
        float w = Wca[n];
        g  = fmaf(vv, w, g);
        s1 += vv;
        s2 = fmaf(vv, vv, s2);
    }
    int idx = (ch * B_ + b) * CO + c;
    Gp[idx] = g; S1p[idx] = s1; S2p[idx] = s2;
}

// ---------------- K4c: finalize gate + BN stats ----------------
__global__ __launch_bounds__(128) void bn_stats_kernel(
    const float* __restrict__ Gp, const float* __restrict__ S1p, const float* __restrict__ S2p,
    const float* __restrict__ bca, float* __restrict__ Gate,
    float* __restrict__ mu, float* __restrict__ rstd)
{
    const int c = threadIdx.x;
    float msum = 0, sqsum = 0;
    for (int b = 0; b < B_; ++b) {
        float g = 0, s1 = 0, s2 = 0;
        for (int ch = 0; ch < 32; ++ch) {
            int idx = (ch * B_ + b) * CO + c;
            g += Gp[idx]; s1 += S1p[idx]; s2 += S2p[idx];
        }
        g += bca[0];
        Gate[b * CO + c] = g;
        msum  = fmaf(g, s1, msum);
        sqsum = fmaf(g * g, s2, sqsum);
    }
    float mean = msum * (1.f / 25088.f);
    float var  = sqsum * (1.f / 25088.f) - mean * mean;
    mu[c] = mean;
    rstd[c] = rsqrtf(var + EPS);
}

// ---------------- K5: transpose + gate + BN + GELU ----------------
__global__ __launch_bounds__(256) void out_kernel(
    const float* __restrict__ ctx, const float* __restrict__ Gate,
    const float* __restrict__ mu, const float* __restrict__ rstd,
    const float* __restrict__ bng, const float* __restrict__ bnb,
    float* __restrict__ out)
{
    __shared__ float T[32][33];
    const int nt = blockIdx.x, ct = blockIdx.y, b = blockIdx.z;
    const int n0 = nt * 32, c0 = ct * 32;
    const int tid = threadIdx.x;
    const int j = tid & 31, i0 = tid >> 5;
    #pragma unroll
    for (int p = 0; p < 4; ++p) {
        int i = i0 + p * 8;
        T[i][j] = ctx[(size_t)(b * N_ + n0 + i) * CO + c0 + j];
    }
    __syncthreads();
    #pragma unroll
    for (int p = 0; p < 4; ++p) {
        int cl = i0 + p * 8;
        int c = c0 + cl;
        float val = Gate[b * CO + c] * T[j][cl];
        val = (val - mu[c]) * rstd[c] * bng[c] + bnb[c];
        out[((size_t)(b * CO + c)) * N_ + n0 + j] = gelu_exact(val);
    }
}

extern "C" void kernel_launch(void* const* d_in, const int* in_sizes, int n_in,
                              void* d_out, int out_size, void* d_ws, size_t ws_size,
                              hipStream_t stream)
{
    const float* x   = (const float*)d_in[0];
    const float* Wq  = (const float*)d_in[1];
    const float* bq  = (const float*)d_in[2];
    const float* gq  = (const float*)d_in[3];
    const float* btq = (const float*)d_in[4];
    const float* Wk  = (const float*)d_in[5];
    const float* bk  = (const float*)d_in[6];
    const float* gk  = (const float*)d_in[7];
    const float* btk = (const float*)d_in[8];
    const float* Wv  = (const float*)d_in[9];
    const float* bv  = (const float*)d_in[10];
    const float* gv  = (const float*)d_in[11];
    const float* btv = (const float*)d_in[12];
    const float* g1  = (const float*)d_in[13];
    const float* b1  = (const float*)d_in[14];
    const float* Wca = (const float*)d_in[15];
    const float* bca = (const float*)d_in[16];
    const float* bng = (const float*)d_in[17];
    const float* bnb = (const float*)d_in[18];
    float* out = (float*)d_out;

    const size_t SZ = (size_t)B_ * N_ * CO;   // 3,211,264
    unsigned short* qb = (unsigned short*)d_ws;
    unsigned short* kb = qb + SZ;
    unsigned short* vt = kb + SZ;
    float* cb   = (float*)(vt + SZ);
    float* Gp   = cb + SZ;
    float* S1p  = Gp + 32768;
    float* S2p  = S1p + 32768;
    float* Gate = S2p + 32768;
    float* muv  = Gate + 1024;
    float* rsv  = muv + 128;
    unsigned short* wimg = (unsigned short*)(rsv + 128);   // 442,368 B

    wprep_kernel<<<dim3(432), 256, 0, stream>>>(Wq, Wk, Wv, wimg);
    qkv_kernel<<<dim3(49, 8), 256, 0, stream>>>(x, wimg,
                                                bq, gq, btq, bk, gk, btk, bv, gv, btv,
                                                qb, kb, vt);
    attn_kernel<<<dim3(49, 8), 256, 0, stream>>>(qb, kb, vt, g1, b1, cb);
    gate_part_kernel<<<dim3(32, 8), 128, 0, stream>>>(cb, Wca, Gp, S1p, S2p);
    bn_stats_kernel<<<dim3(1), 128, 0, stream>>>(Gp, S1p, S2p, bca, Gate, muv, rsv);
    out_kernel<<<dim3(98, 4, 8), 256, 0, stream>>>(cb, Gate, muv, rsv, bng, bnb, out);
}